// Round 12
// baseline (168.762 us; speedup 1.0000x reference)
//
#include <hip/hip_runtime.h>

#define HW 4096
#define KC 512

typedef __attribute__((ext_vector_type(8))) short s16x8;
typedef __attribute__((ext_vector_type(16))) float f32x16;

__device__ inline short f2bf(float f) {          // RTNE float->bf16
    unsigned int u = __builtin_bit_cast(unsigned int, f);
    unsigned int lsb = (u >> 16) & 1u;
    u += 0x7fffu + lsb;
    return (short)(u >> 16);
}
__device__ inline float bf2f(short h) {
    unsigned int u = ((unsigned int)(unsigned short)h) << 16;
    return __builtin_bit_cast(float, u);
}

// ws byte layout:
//   0       cnt f32[512]                  (zeroed)
//   2048    avg f32[32768]                (zeroed)
//   133120  loss f32[1]                   (zeroed)
//   133136  en f32[512]
//   135184  ehfrag short[16*5*64*8]  80KB (codes hi + en hi/lo cols, K=80)
//   217104  elfrag short[16*4*64*8]  64KB (codes lo, K=64)
//   282640  cand u32[131072]  (k_argmin: top-2 pair; k_quant rewrites winner; k_seg reads)
#define WS_EN    133136
#define WS_EHF   135184
#define WS_ELF   217104
#define WS_CAND  282640

__global__ void k_prep_en(const float* __restrict__ emb, float* __restrict__ en) {
    int m = blockIdx.x * 256 + threadIdx.x;
    if (m >= KC) return;
    const float* e = emb + m * 64;
    float d0 = 0.f, d1 = 0.f, d2 = 0.f, d3 = 0.f;
#pragma unroll
    for (int c = 0; c < 64; c += 4) {
        d0 = fmaf(e[c], e[c], d0);
        d1 = fmaf(e[c + 1], e[c + 1], d1);
        d2 = fmaf(e[c + 2], e[c + 2], d2);
        d3 = fmaf(e[c + 3], e[c + 3], d3);
    }
    en[m] = (d0 + d1) + (d2 + d3);
}

// Build pre-swizzled A-fragments (32x32x16 layout: m=lane&31, k=(lane>>5)*8+j).
__global__ void k_prep_frag(const float* __restrict__ emb, const float* __restrict__ en,
                            short* __restrict__ ehf, short* __restrict__ elf) {
    int t = blockIdx.x * 256 + threadIdx.x;   // 0..4095
    int m = t >> 3, ko = t & 7;
    int mt = m >> 5, ks = ko >> 1;
    int lane = (m & 31) + 32 * (ko & 1);
    s16x8 hv, lv;
#pragma unroll
    for (int j = 0; j < 8; ++j) {
        float v = emb[m * 64 + ko * 8 + j];
        short h = f2bf(v);
        hv[j] = h;
        lv[j] = f2bf(v - bf2f(h));
    }
    ((s16x8*)ehf)[(mt * 5 + ks) * 64 + lane] = hv;
    ((s16x8*)elf)[(mt * 4 + ks) * 64 + lane] = lv;

    // ks=4 block of ehf: k=64 -> en_hi, k=65 -> en_lo, rest 0. One u32 per thread.
    int e2 = t * 2;
    int mt2 = e2 >> 9;
    int lane2 = (e2 >> 3) & 63;
    int j2 = e2 & 7;
    unsigned int val = 0;
    if (lane2 < 32 && j2 == 0) {
        float ev = en[mt2 * 32 + (lane2 & 31)];
        short eh_ = f2bf(ev);
        short el_ = f2bf(ev - bf2f(eh_));
        val = ((unsigned int)(unsigned short)eh_) | (((unsigned int)(unsigned short)el_) << 16);
    }
    *(unsigned int*)(ehf + ((size_t)(mt2 * 5 + 4) * 64 + lane2) * 8 + j2) = val;
}

__device__ inline void merge2(float& s1, int& i1, float& s2, int& i2,
                              float os1, int oi1, float os2, int oi2) {
    bool ob = (os1 < s1) || (os1 == s1 && oi1 < i1);
    float n1s = ob ? os1 : s1;  int n1i = ob ? oi1 : i1;
    float ls  = ob ? s1  : os1; int li  = ob ? i1  : oi1;  // losing first
    float ws  = ob ? os2 : s2;  int wi  = ob ? oi2 : i2;   // winner's second
    bool b2 = (ls < ws) || (ls == ws && li < wi);
    s1 = n1s; i1 = n1i;
    s2 = b2 ? ls : ws; i2 = b2 ? li : wi;
}

// MFMA-only kernel: 256 threads = 4 independent waves, 32 tokens/wave,
// grid 1024 -> 4096 waves = 4 waves/SIMD. No epilogue -> ~105 live VGPRs fit
// the 128-VGPR/4-wave budget NATURALLY (no occupancy attribute - R6/R8's
// forced attributes starved the allocator). Emits packed top-2 candidates.
__global__ __launch_bounds__(256) void k_argmin(const float* __restrict__ x,
                                                const short* __restrict__ ehf,
                                                const short* __restrict__ elf,
                                                unsigned int* __restrict__ cand) {
    int tid = threadIdx.x;
    int wv = tid >> 6, lane = tid & 63;
    int tb = blockIdx.x * 128;                 // 128 tokens per block
    int n = tb >> 12, hwb = tb & 4095;
    const float* xp = x + (size_t)n * 64 * HW;
    int wbase = hwb + wv * 32;

    int l5 = lane & 31;
    int kh = (lane >> 5) * 8;    // k-half channel offset

    // ---- direct-to-fragment loads of x~ = -2x (hi/lo bf16) ----
    s16x8 fh[5], fl[4];
    {
        const float* pa = xp + wbase + l5;
#pragma unroll
        for (int ks = 0; ks < 4; ++ks) {
            s16x8 ha, la;
#pragma unroll
            for (int j = 0; j < 8; ++j) {
                int c = ks * 16 + kh + j;
                float va = -2.0f * pa[(size_t)c * HW];
                short h0 = f2bf(va); ha[j] = h0; la[j] = f2bf(va - bf2f(h0));
            }
            fh[ks] = ha; fl[ks] = la;
        }
        s16x8 v0;
#pragma unroll
        for (int j = 0; j < 8; ++j) v0[j] = 0;
        if (lane < 32) { v0[0] = (short)0x3F80; v0[1] = (short)0x3F80; }
        fh[4] = v0;
    }

    const s16x8* eh8 = (const s16x8*)ehf;
    const s16x8* el8 = (const s16x8*)elf;

    float s1 = 3.402823466e38f, s2 = 3.402823466e38f;
    int i1 = 0, i2 = 0;
    int hv4 = (lane >> 5) * 4;

#pragma unroll 2
    for (int mt = 0; mt < 16; ++mt) {
        s16x8 ah[5], al[4];
#pragma unroll
        for (int ks = 0; ks < 5; ++ks) ah[ks] = eh8[(mt * 5 + ks) * 64 + lane];
#pragma unroll
        for (int ks = 0; ks < 4; ++ks) al[ks] = el8[(mt * 4 + ks) * 64 + lane];

        f32x16 acc;
#pragma unroll
        for (int r = 0; r < 16; ++r) acc[r] = 0.0f;
#pragma unroll
        for (int ks = 0; ks < 5; ++ks)
            acc = __builtin_amdgcn_mfma_f32_32x32x16_bf16(ah[ks], fh[ks], acc, 0, 0, 0);
#pragma unroll
        for (int ks = 0; ks < 4; ++ks)
            acc = __builtin_amdgcn_mfma_f32_32x32x16_bf16(al[ks], fh[ks], acc, 0, 0, 0);
#pragma unroll
        for (int ks = 0; ks < 4; ++ks)
            acc = __builtin_amdgcn_mfma_f32_32x32x16_bf16(ah[ks], fl[ks], acc, 0, 0, 0);

        int mb = mt * 32 + hv4;
#pragma unroll
        for (int r = 0; r < 16; ++r) {
            int mi = mb + (r & 3) + 8 * (r >> 2);
            float s = acc[r];
            bool c1 = s < s1, c2 = s < s2;
            s2 = c1 ? s1 : (c2 ? s : s2); i2 = c1 ? i1 : (c2 ? mi : i2);
            s1 = c1 ? s : s1;             i1 = c1 ? mi : i1;
        }
    }

    // lanes l and l^32 hold disjoint code-rows of the same token: merge
    merge2(s1, i1, s2, i2, __shfl_xor(s1, 32), __shfl_xor(i1, 32),
           __shfl_xor(s2, 32), __shfl_xor(i2, 32));

    if (lane < 32)
        cand[tb + wv * 32 + l5] = (unsigned int)i1 | ((unsigned int)i2 << 16);
}

// Streaming rescore+write kernel: 1 thread = 1 token. Exact fp32 rescore of
// both candidates (same arithmetic as all passing rounds), winner -> cand
// (in place, u32), quantized NCHW write + loss partial. High TLP hides the
// strided x loads and divergent emb row gathers.
__global__ __launch_bounds__(256) void k_quant(const float* __restrict__ x,
                                               const float* __restrict__ emb,
                                               const float* __restrict__ en,
                                               unsigned int* __restrict__ cand,
                                               float* __restrict__ qout,
                                               float* __restrict__ loss_acc) {
    int t = blockIdx.x * 256 + threadIdx.x;
    int n = t >> 12, hw = t & 4095;
    const float* xq = x + (size_t)n * 64 * HW + hw;

    float xv[64];
#pragma unroll
    for (int c = 0; c < 64; ++c) xv[c] = xq[(size_t)c * HW];

    unsigned int cd = cand[t];
    int c1 = (int)(cd & 0xffffu), c2 = (int)(cd >> 16);
    int ia = (c1 < c2) ? c1 : c2;
    int ib = (c1 < c2) ? c2 : c1;

    float sxx;
    {
        float d0 = 0.f, d1 = 0.f, d2 = 0.f, d3 = 0.f;
#pragma unroll
        for (int c = 0; c < 64; c += 4) {
            d0 = fmaf(xv[c], xv[c], d0);
            d1 = fmaf(xv[c + 1], xv[c + 1], d1);
            d2 = fmaf(xv[c + 2], xv[c + 2], d2);
            d3 = fmaf(xv[c + 3], xv[c + 3], d3);
        }
        sxx = (d0 + d1) + (d2 + d3);
    }

    float sa, sb;
    {
        const float4* er = (const float4*)(emb + (size_t)ia * 64);
        float d0 = 0.f, d1 = 0.f, d2 = 0.f, d3 = 0.f;
#pragma unroll
        for (int q = 0; q < 16; ++q) {
            float4 e4 = er[q];
            d0 = fmaf(xv[q * 4], e4.x, d0);
            d1 = fmaf(xv[q * 4 + 1], e4.y, d1);
            d2 = fmaf(xv[q * 4 + 2], e4.z, d2);
            d3 = fmaf(xv[q * 4 + 3], e4.w, d3);
        }
        sa = (sxx + en[ia]) - 2.0f * ((d0 + d1) + (d2 + d3));
    }
    {
        const float4* er = (const float4*)(emb + (size_t)ib * 64);
        float d0 = 0.f, d1 = 0.f, d2 = 0.f, d3 = 0.f;
#pragma unroll
        for (int q = 0; q < 16; ++q) {
            float4 e4 = er[q];
            d0 = fmaf(xv[q * 4], e4.x, d0);
            d1 = fmaf(xv[q * 4 + 1], e4.y, d1);
            d2 = fmaf(xv[q * 4 + 2], e4.z, d2);
            d3 = fmaf(xv[q * 4 + 3], e4.w, d3);
        }
        sb = (sxx + en[ib]) - 2.0f * ((d0 + d1) + (d2 + d3));
    }
    int win = (sb < sa) ? ib : ia;   // tie -> lower index (ia < ib)
    cand[t] = (unsigned int)win;

    // quantized write + loss
    const float4* ew = (const float4*)(emb + (size_t)win * 64);
    float* qp = qout + (size_t)n * 64 * HW + hw;
    float l0 = 0.f, l1 = 0.f, l2 = 0.f, l3 = 0.f;
#pragma unroll
    for (int q = 0; q < 16; ++q) {
        float4 e4 = ew[q];
        qp[(size_t)(q * 4) * HW] = e4.x;
        qp[(size_t)(q * 4 + 1) * HW] = e4.y;
        qp[(size_t)(q * 4 + 2) * HW] = e4.z;
        qp[(size_t)(q * 4 + 3) * HW] = e4.w;
        float f0 = xv[q * 4] - e4.x, f1 = xv[q * 4 + 1] - e4.y;
        float f2 = xv[q * 4 + 2] - e4.z, f3 = xv[q * 4 + 3] - e4.w;
        l0 = fmaf(f0, f0, l0);
        l1 = fmaf(f1, f1, l1);
        l2 = fmaf(f2, f2, l2);
        l3 = fmaf(f3, f3, l3);
    }
    float lp = (l0 + l1) + (l2 + l3);
#pragma unroll
    for (int off = 32; off; off >>= 1) lp += __shfl_down(lp, off);
    if ((threadIdx.x & 63) == 0) atomicAdd(loss_acc, lp);
}

// grid = (32 images) x (8 channel-groups) x (2 hw-halves) = 512 blocks.
// LDS acc [512][9] (9 coprime to 32 banks). Winner idx read as u32.
__global__ __launch_bounds__(1024) void k_seg(const float* __restrict__ x,
                                              const unsigned int* __restrict__ idx,
                                              float* __restrict__ cnt_g,
                                              float* __restrict__ avg_g) {
    __shared__ float acc[KC * 9];
    __shared__ float cnt[KC];
    int tid = threadIdx.x;
    int b = blockIdx.x;
    int n = b >> 4;
    int cg = (b >> 1) & 7;
    int h = b & 1;

    for (int i = tid; i < KC * 9; i += 1024) acc[i] = 0.f;
    if (cg == 0 && tid < KC) cnt[tid] = 0.f;
    __syncthreads();

    const float* xp = x + (size_t)n * 64 * HW + (size_t)(cg * 8) * HW + h * 2048;
    const unsigned int* ip = idx + n * HW + h * 2048;

#pragma unroll
    for (int p = 0; p < 2; ++p) {
        int hw = p * 1024 + tid;
        int k = (int)ip[hw];
        if (cg == 0) atomicAdd(&cnt[k], 1.0f);
        float* row = acc + k * 9;
#pragma unroll
        for (int j = 0; j < 8; ++j) {
            atomicAdd(&row[j], xp[(size_t)j * HW + hw]);
        }
    }
    __syncthreads();

    for (int i = tid; i < KC * 8; i += 1024) {
        int k = i >> 3, j = i & 7;
        atomicAdd(&avg_g[k * 64 + cg * 8 + j], acc[k * 9 + j]);
    }
    if (cg == 0 && tid < KC) atomicAdd(&cnt_g[tid], cnt[tid]);
}

__global__ void k_fin(const float* __restrict__ cs_in, const float* __restrict__ avg_in,
                      const float* __restrict__ cnt, const float* __restrict__ avgacc,
                      const float* __restrict__ loss_acc,
                      float* __restrict__ loss_out, float* __restrict__ emb_out,
                      float* __restrict__ cs_out, float* __restrict__ avg_out) {
    int i = blockIdx.x * 256 + threadIdx.x;
    if (i >= KC * 64) return;
    int k = i >> 6, c = i & 63;
    float ncs = cs_in[k] * 0.99f + 0.01f * cnt[k];
    float nav = avg_in[i] * 0.99f + 0.01f * avgacc[i];
    avg_out[i] = nav;
    emb_out[i] = nav / (ncs + 1e-5f);
    if (c == 0) cs_out[k] = ncs;
    if (i == 0) loss_out[0] = loss_acc[0] * (1.0f / 8388608.0f);
}

extern "C" void kernel_launch(void* const* d_in, const int* in_sizes, int n_in,
                              void* d_out, int out_size, void* d_ws, size_t ws_size,
                              hipStream_t stream) {
    (void)in_sizes; (void)n_in; (void)out_size; (void)ws_size;
    const float* x   = (const float*)d_in[0];
    const float* emb = (const float*)d_in[1];
    const float* cs  = (const float*)d_in[2];
    const float* avg = (const float*)d_in[3];

    float* out      = (float*)d_out;
    float* qout     = out;
    float* loss_out = out + 8388608;
    float* emb_out  = loss_out + 1;
    float* cs_out   = emb_out + 32768;
    float* avg_out  = cs_out + 512;

    char* wsb = (char*)d_ws;
    float* cnt_acc  = (float*)wsb;
    float* avg_acc  = (float*)(wsb + 2048);
    float* loss_acc = (float*)(wsb + 133120);
    float* en       = (float*)(wsb + WS_EN);
    short* ehf      = (short*)(wsb + WS_EHF);
    short* elf      = (short*)(wsb + WS_ELF);
    unsigned int* cand = (unsigned int*)(wsb + WS_CAND);

    hipMemsetAsync(d_ws, 0, 133124, stream);
    k_prep_en<<<2, 256, 0, stream>>>(emb, en);
    k_prep_frag<<<16, 256, 0, stream>>>(emb, en, ehf, elf);
    k_argmin<<<1024, 256, 0, stream>>>(x, ehf, elf, cand);
    k_quant<<<512, 256, 0, stream>>>(x, emb, en, cand, qout, loss_acc);
    k_seg<<<512, 1024, 0, stream>>>(x, cand, cnt_acc, avg_acc);
    k_fin<<<128, 256, 0, stream>>>(cs, avg, cnt_acc, avg_acc, loss_acc,
                                   loss_out, emb_out, cs_out, avg_out);
}